// Round 3
// baseline (596.118 us; speedup 1.0000x reference)
//
#include <hip/hip_runtime.h>
#include <hip/hip_bf16.h>

typedef __bf16  bf16x8 __attribute__((ext_vector_type(8)));
typedef __bf16  bf16x4 __attribute__((ext_vector_type(4)));
typedef float   f32x4  __attribute__((ext_vector_type(4)));
typedef __hip_bfloat16 bf;

__device__ __forceinline__ float clamp256(float v) {
    return fminf(fmaxf(v, -256.f), 256.f);
}
__device__ __forceinline__ float sane(float v) {
    return fminf(fmaxf(v, -1e4f), 1e4f);
}

// ---------------------------------------------------------------------------
// Tap-fused, register-prefetch 64x64 bf16 MFMA GEMM (legacy: GAT + FC head).
// mode 0: store (+bias,relu) -> outb bf16 or outf f32
// mode 2: register-resident LayerNorm(nn)+relu+residual (accR/Wd or res[])
// mode 3: split-K bf16 partials: outb[z*M*ostride + row*ostride + col]
// mode 5: dual output (HASWD): outb=accC+bias, res(cast bf*)=accR+biasd
// ---------------------------------------------------------------------------
template<int TAPS, bool HASWD>
__global__ __launch_bounds__(256) void gemm_tf(
    const bf* __restrict__ A, const bf* __restrict__ Wt, const bf* __restrict__ Wd,
    const float* __restrict__ bias, const float* __restrict__ biasd,
    const float* __restrict__ lnw, const float* __restrict__ lnb,
    const bf* __restrict__ res, int res_stride,
    bf* __restrict__ outb, float* __restrict__ outf, int out_stride,
    int M, int N, int K, int dil, int mode, int relu, int padded, int nn, int kLen)
{
    constexpr int NT = TAPS + (HASWD ? 1 : 0);
    __shared__ __align__(16) unsigned short sA[66 * 40];      // 64 rows + zero row 64
    __shared__ __align__(16) unsigned short sB[NT][64 * 40];
    __shared__ float sS[4][64], sS2[4][64];

    const int tid  = threadIdx.x;
    const int wv   = tid >> 6;
    const int lane = tid & 63;
    const int m0   = blockIdx.y * 64;
    const int n0   = blockIdx.x * 64;
    const int frow = lane & 15;
    const int fq   = lane >> 4;
    const int kOff = blockIdx.z * kLen;
    const int kEnd = (kOff + kLen < K) ? (kOff + kLen) : K;

    if (tid < 40) sA[64 * 40 + tid] = (unsigned short)0;

    int aoff[NT];
    {
        int token = wv * 16 + frow;
        int b = token >> 5, l = token & 31;
        #pragma unroll
        for (int t = 0; t < NT; ++t) {
            int s = (t < TAPS) ? (t - TAPS / 2) * dil : 0;
            int ar;
            if (padded) {
                int ls = l + s;
                ar = ((unsigned)ls < 32u) ? (b * 32 + ls) : 64;
            } else {
                ar = token;
            }
            aoff[t] = ar * 40 + fq * 8;
        }
    }

    const int srow = tid >> 2;
    const int schk = (tid & 3) << 3;
    int raG = m0 + srow;
    if (!padded && raG >= M) raG = -1;
    const int rbG  = n0 + srow;
    const bool bval = rbG < N;
    const bf* Ap = (raG >= 0) ? (A + (size_t)raG * K) : nullptr;
    const bf* Bp[NT];
    #pragma unroll
    for (int t = 0; t < NT; ++t)
        Bp[t] = (HASWD && t == TAPS) ? (Wd + (size_t)rbG * K)
                                     : (Wt + ((size_t)t * N + rbG) * K);

    f32x4 accC[4], accR[4];
    #pragma unroll
    for (int i = 0; i < 4; ++i) { accC[i] = 0.f; accR[i] = 0.f; }

    const uint4 zu = make_uint4(0u, 0u, 0u, 0u);
    uint4 pa, pb[NT];
    pa = Ap ? *(const uint4*)(Ap + kOff + schk) : zu;
    #pragma unroll
    for (int t = 0; t < NT; ++t)
        pb[t] = bval ? *(const uint4*)(Bp[t] + kOff + schk) : zu;

    for (int kb = kOff; kb < kEnd; kb += 32) {
        __syncthreads();
        *(uint4*)(sA + srow * 40 + schk) = pa;
        #pragma unroll
        for (int t = 0; t < NT; ++t)
            *(uint4*)(&sB[t][srow * 40 + schk]) = pb[t];
        __syncthreads();
        int kn = kb + 32;
        if (kn < kEnd) {
            pa = Ap ? *(const uint4*)(Ap + kn + schk) : zu;
            #pragma unroll
            for (int t = 0; t < NT; ++t)
                pb[t] = bval ? *(const uint4*)(Bp[t] + kn + schk) : zu;
        }
        #pragma unroll
        for (int t = 0; t < TAPS; ++t) {
            bf16x8 af = *(const bf16x8*)(sA + aoff[t]);
            #pragma unroll
            for (int nt = 0; nt < 4; ++nt) {
                bf16x8 bg = *(const bf16x8*)(&sB[t][(nt * 16 + frow) * 40 + fq * 8]);
                accC[nt] = __builtin_amdgcn_mfma_f32_16x16x32_bf16(af, bg, accC[nt], 0, 0, 0);
            }
        }
        if constexpr (HASWD) {
            bf16x8 af = *(const bf16x8*)(sA + aoff[TAPS]);
            #pragma unroll
            for (int nt = 0; nt < 4; ++nt) {
                bf16x8 bg = *(const bf16x8*)(&sB[TAPS][(nt * 16 + frow) * 40 + fq * 8]);
                accR[nt] = __builtin_amdgcn_mfma_f32_16x16x32_bf16(af, bg, accR[nt], 0, 0, 0);
            }
        }
    }

    if (mode == 0) {
        #pragma unroll
        for (int nt = 0; nt < 4; ++nt) {
            int col = n0 + nt * 16 + frow;
            if (col >= N) continue;
            float bv = bias ? bias[col] : 0.f;
            #pragma unroll
            for (int r = 0; r < 4; ++r) {
                int row = m0 + wv * 16 + fq * 4 + r;
                if (row >= M) continue;
                float v = accC[nt][r] + bv;
                if (relu) v = fmaxf(v, 0.f);
                if (outb) outb[(size_t)row * out_stride + col] = __float2bfloat16(clamp256(v));
                else      outf[(size_t)row * out_stride + col] = sane(v);
            }
        }
    } else if (mode == 3) {
        bf* po = outb + (size_t)blockIdx.z * M * out_stride;
        #pragma unroll
        for (int nt = 0; nt < 4; ++nt) {
            int col = n0 + nt * 16 + frow;
            if (col >= N) continue;
            #pragma unroll
            for (int r = 0; r < 4; ++r) {
                int row = m0 + wv * 16 + fq * 4 + r;
                if (row >= M) continue;
                po[(size_t)row * out_stride + col] = __float2bfloat16(accC[nt][r]);
            }
        }
    } else if (mode == 5) {
        if constexpr (HASWD) {
            bf* out2 = (bf*)res;
            #pragma unroll
            for (int nt = 0; nt < 4; ++nt) {
                int col = n0 + nt * 16 + frow;
                if (col >= N) continue;
                float bv = bias[col], bd = biasd[col];
                #pragma unroll
                for (int r = 0; r < 4; ++r) {
                    int row = m0 + wv * 16 + fq * 4 + r;
                    if (row >= M) continue;
                    outb[(size_t)row * out_stride + col] = __float2bfloat16(clamp256(accC[nt][r] + bv));
                    out2[(size_t)row * res_stride + col] = __float2bfloat16(clamp256(accR[nt][r] + bd));
                }
            }
        }
    } else {  // mode 2
        float bvc[4], bdc[4];
        #pragma unroll
        for (int nt = 0; nt < 4; ++nt) {
            int col = n0 + nt * 16 + frow;
            bvc[nt] = bias[col];
            bdc[nt] = (HASWD && biasd) ? biasd[col] : 0.f;
        }
        float s[4], s2[4];
        #pragma unroll
        for (int nt = 0; nt < 4; ++nt) { s[nt] = 0.f; s2[nt] = 0.f; }
        #pragma unroll
        for (int nt = 0; nt < 4; ++nt)
            #pragma unroll
            for (int r = 0; r < 4; ++r) {
                int row = wv * 16 + fq * 4 + r;
                int l = row & 31;
                float v = sane(accC[nt][r] + bvc[nt]);
                if (l < nn) { s[nt] += v; s2[nt] += v * v; }
            }
        #pragma unroll
        for (int nt = 0; nt < 4; ++nt) {
            s[nt]  += __shfl_xor(s[nt], 16);  s[nt]  += __shfl_xor(s[nt], 32);
            s2[nt] += __shfl_xor(s2[nt], 16); s2[nt] += __shfl_xor(s2[nt], 32);
        }
        if (fq == 0) {
            #pragma unroll
            for (int nt = 0; nt < 4; ++nt) {
                sS[wv][nt * 16 + frow]  = s[nt];
                sS2[wv][nt * 16 + frow] = s2[nt];
            }
        }
        __syncthreads();
        const int gi = wv >> 1;
        const float inv = 1.f / (float)nn;
        #pragma unroll
        for (int nt = 0; nt < 4; ++nt) {
            int c = nt * 16 + frow;
            int colg = n0 + c;
            float S  = sS[2 * gi][c]  + sS[2 * gi + 1][c];
            float S2 = sS2[2 * gi][c] + sS2[2 * gi + 1][c];
            float mu = S * inv;
            float var = S2 * inv - mu * mu;
            float rs = rsqrtf(fmaxf(var, 0.f) + 1e-5f);
            #pragma unroll
            for (int r = 0; r < 4; ++r) {
                int row = wv * 16 + fq * 4 + r;
                int l = row & 31;
                int grow = m0 + row;
                float outv = 0.f;
                if (l < nn) {
                    float v = (sane(accC[nt][r] + bvc[nt]) - mu) * rs * lnw[l] + lnb[l];
                    v = fmaxf(v, 0.f);
                    float rr;
                    if constexpr (HASWD) rr = sane(accR[nt][r] + bdc[nt]);
                    else rr = __bfloat162float(res[(size_t)grow * res_stride + colg]);
                    outv = clamp256(v + rr);
                }
                outb[(size_t)grow * out_stride + colg] = __float2bfloat16(outv);
            }
        }
    }
}

// ---------------------------------------------------------------------------
// TCN-specialized tap-fused GEMM v2: 128x64 macro-tile, each wave owns a
// 64x... -> 32-row graph x 64 cols sub-tile pair (MR=2 m-reps, one GRAPH per
// wave). Register budget ~115 (acc 64 + prefetch 24 + addr) fits 128 VGPR
// -> no loop spill (round-2 showed 256-tile spilled at VGPR=164).
// __launch_bounds__(256,4): 4 waves/SIMD target -> 4 blocks/CU resident.
// In-register LayerNorm: the wave's 32 rows = exactly one graph.
// Requires: M % 128 == 0, N % 64 == 0, K % 32 == 0.
// ---------------------------------------------------------------------------
template<int TAPS, bool HASWD>
__global__ __launch_bounds__(256, 4) void gemm_tcn(
    const bf* __restrict__ A, const bf* __restrict__ Wt, const bf* __restrict__ Wd,
    const float* __restrict__ bias, const float* __restrict__ biasd,
    const float* __restrict__ lnw, const float* __restrict__ lnb,
    const bf* __restrict__ res, int res_stride,
    bf* __restrict__ outb, int out_stride,
    int M, int N, int K, int dil, int nn)
{
    constexpr int NT = TAPS + (HASWD ? 1 : 0);
    __shared__ __align__(16) unsigned short sA[130 * 40];     // 128 rows + zero row 128
    __shared__ __align__(16) unsigned short sB[NT][64 * 40];

    const int tid  = threadIdx.x;
    const int wv   = tid >> 6;
    const int lane = tid & 63;
    const int frow = lane & 15;
    const int fq   = lane >> 4;

    // XCD-contiguous swizzle (bijective when nwg % 8 == 0)
    const int gx  = gridDim.x;
    const int nwg = gx * gridDim.y;
    int wg = blockIdx.y * gx + blockIdx.x;
    if ((nwg & 7) == 0) wg = (wg & 7) * (nwg >> 3) + (wg >> 3);
    const int n0 = (wg % gx) * 64;
    const int m0 = (wg / gx) * 128;

    if (tid < 40) sA[128 * 40 + tid] = (unsigned short)0;

    // A fragment LDS offsets per (tap, m-rep); zero row = 128.
    // wave wv owns block-local rows [wv*32, wv*32+32) = one graph.
    int aoff[TAPS][2];
    #pragma unroll
    for (int mr = 0; mr < 2; ++mr) {
        int l = mr * 16 + frow;                               // row within graph
        #pragma unroll
        for (int t = 0; t < TAPS; ++t) {
            int ls = l + (t - TAPS / 2) * dil;
            int ar = ((unsigned)ls < 32u) ? (wv * 32 + ls) : 128;
            aoff[t][mr] = ar * 40 + fq * 8;
        }
    }

    // staging: thread covers A rows {tid>>2, tid>>2 + 64}, B row tid>>2
    const int srow = tid >> 2;
    const int chS  = (tid & 3) << 3;                          // shorts
    const bf* Ap = A + (size_t)(m0 + srow) * K + chS;
    const bf* Bp[NT];
    #pragma unroll
    for (int t = 0; t < NT; ++t)
        Bp[t] = (HASWD && t == TAPS) ? (Wd + (size_t)(n0 + srow) * K + chS)
                                     : (Wt + ((size_t)t * N + n0 + srow) * K + chS);

    f32x4 accC[2][4], accR[2][4];                             // [mr][nt]
    #pragma unroll
    for (int i = 0; i < 2; ++i)
        #pragma unroll
        for (int j = 0; j < 4; ++j) { accC[i][j] = 0.f; if (HASWD) accR[i][j] = 0.f; }

    uint4 pa[2], pb[NT];
    #pragma unroll
    for (int i = 0; i < 2; ++i) pa[i] = *(const uint4*)(Ap + (size_t)i * 64 * K);
    #pragma unroll
    for (int t = 0; t < NT; ++t) pb[t] = *(const uint4*)(Bp[t]);

    for (int kb = 0; kb < K; kb += 32) {
        __syncthreads();
        #pragma unroll
        for (int i = 0; i < 2; ++i)
            *(uint4*)(sA + (srow + i * 64) * 40 + chS) = pa[i];
        #pragma unroll
        for (int t = 0; t < NT; ++t)
            *(uint4*)(&sB[t][srow * 40 + chS]) = pb[t];
        __syncthreads();
        int kn = kb + 32;
        if (kn < K) {
            #pragma unroll
            for (int i = 0; i < 2; ++i)
                pa[i] = *(const uint4*)(Ap + (size_t)i * 64 * K + kn);
            #pragma unroll
            for (int t = 0; t < NT; ++t)
                pb[t] = *(const uint4*)(Bp[t] + kn);
        }
        bf16x8 aMid[2];
        #pragma unroll
        for (int mr = 0; mr < 2; ++mr)
            aMid[mr] = *(const bf16x8*)(sA + aoff[TAPS / 2][mr]);
        #pragma unroll
        for (int t = 0; t < TAPS; ++t) {
            bf16x8 af[2];
            #pragma unroll
            for (int mr = 0; mr < 2; ++mr)
                af[mr] = (t == TAPS / 2) ? aMid[mr]
                                         : *(const bf16x8*)(sA + aoff[t][mr]);
            #pragma unroll
            for (int nt = 0; nt < 4; ++nt) {
                bf16x8 bg = *(const bf16x8*)(&sB[t][(nt * 16 + frow) * 40 + fq * 8]);
                #pragma unroll
                for (int mr = 0; mr < 2; ++mr)
                    accC[mr][nt] = __builtin_amdgcn_mfma_f32_16x16x32_bf16(af[mr], bg, accC[mr][nt], 0, 0, 0);
            }
        }
        if constexpr (HASWD) {
            #pragma unroll
            for (int nt = 0; nt < 4; ++nt) {
                bf16x8 bg = *(const bf16x8*)(&sB[TAPS][(nt * 16 + frow) * 40 + fq * 8]);
                #pragma unroll
                for (int mr = 0; mr < 2; ++mr)
                    accR[mr][nt] = __builtin_amdgcn_mfma_f32_16x16x32_bf16(aMid[mr], bg, accR[mr][nt], 0, 0, 0);
            }
        }
    }

    // ---- epilogue: in-register LayerNorm(nn) + relu + residual ----
    float bvc[4], bdc[4];
    #pragma unroll
    for (int nt = 0; nt < 4; ++nt) {
        int col = n0 + nt * 16 + frow;
        bvc[nt] = bias[col];
        bdc[nt] = HASWD ? biasd[col] : 0.f;
    }
    float S[4], Q[4];
    #pragma unroll
    for (int nt = 0; nt < 4; ++nt) { S[nt] = 0.f; Q[nt] = 0.f; }
    #pragma unroll
    for (int mr = 0; mr < 2; ++mr)
        #pragma unroll
        for (int nt = 0; nt < 4; ++nt)
            #pragma unroll
            for (int r = 0; r < 4; ++r) {
                int l = mr * 16 + fq * 4 + r;
                if (l < nn) {
                    float v = sane(accC[mr][nt][r] + bvc[nt]);
                    S[nt] += v; Q[nt] += v * v;
                }
            }
    const float inv = 1.f / (float)nn;
    float mu[4], rsg[4];
    #pragma unroll
    for (int nt = 0; nt < 4; ++nt) {
        float s = S[nt], q = Q[nt];
        s += __shfl_xor(s, 16); s += __shfl_xor(s, 32);
        q += __shfl_xor(q, 16); q += __shfl_xor(q, 32);
        float m = s * inv;
        float var = q * inv - m * m;
        mu[nt]  = m;
        rsg[nt] = rsqrtf(fmaxf(var, 0.f) + 1e-5f);
    }
    float lw[2][4], lb2[2][4];
    #pragma unroll
    for (int p = 0; p < 2; ++p)
        #pragma unroll
        for (int r = 0; r < 4; ++r) {
            int l = p * 16 + fq * 4 + r;
            bool ok = l < nn;
            lw[p][r]  = ok ? lnw[l] : 0.f;
            lb2[p][r] = ok ? lnb[l] : 0.f;
        }
    // row-outer, nt-inner store order: 4 x 32B segments of one 128B line
    // issue back-to-back -> better write combining.
    #pragma unroll
    for (int mr = 0; mr < 2; ++mr) {
        #pragma unroll
        for (int r = 0; r < 4; ++r) {
            int l = mr * 16 + fq * 4 + r;
            int grow = m0 + wv * 32 + l;
            bf* orow = outb + (size_t)grow * out_stride + n0;
            const bf* rrow = res ? (res + (size_t)grow * res_stride + n0) : nullptr;
            #pragma unroll
            for (int nt = 0; nt < 4; ++nt) {
                float outv = 0.f;
                if (l < nn) {
                    float v = (sane(accC[mr][nt][r] + bvc[nt]) - mu[nt]) * rsg[nt] * lw[mr][r] + lb2[mr][r];
                    v = fmaxf(v, 0.f);
                    float rr;
                    if constexpr (HASWD) rr = sane(accR[mr][nt][r] + bdc[nt]);
                    else rr = __bfloat162float(rrow[nt * 16 + frow]);
                    outv = clamp256(v + rr);
                }
                orow[nt * 16 + frow] = __float2bfloat16(outv);
            }
        }
    }
}

// ---------------------------------------------------------------------------
// Fused per-graph GAT v3: latency-flattened.
// ---------------------------------------------------------------------------
#define MAXNE 270
#define XLS   260   // padded XL row stride (channels)
__global__ __launch_bounds__(256, 4) void gat_fused3(
    const int* __restrict__ ei, const bf* __restrict__ xlb, const bf* __restrict__ xrb,
    const float* __restrict__ att, const float* __restrict__ gbias,
    bf* __restrict__ hbuf, float* __restrict__ dalpha, float* __restrict__ dei,
    int E0, int ET, int EPG, int nn)
{
    __shared__ __align__(16) __bf16 sXL[32 * XLS];   // 16.25 KB (padded rows)
    __shared__ __align__(16) __bf16 sXR[32 * 256];   // 16 KB
    __shared__ float sExp[MAXNE * 4];                // 4.2 KB
    __shared__ int   sSrc[MAXNE], sDst[MAXNE];
    __shared__ int   sList[MAXNE];
    __shared__ int   sCnt[32];
    __shared__ int   sOff[33];

    const int g = blockIdx.x, tid = threadIdx.x, wv = tid >> 6, lane = tid & 63;
    if (EPG + nn > MAXNE) return;
    const int NE = EPG + nn;

    // Phase 0a: load edges (graph-local, clamped) + self loops; stage xl/xr
    for (int k = tid; k < EPG; k += 256) {
        int s = ei[(size_t)g * EPG + k] - g * nn;
        int d = ei[(size_t)E0 + (size_t)g * EPG + k] - g * nn;
        sSrc[k] = min(max(s, 0), nn - 1);
        sDst[k] = min(max(d, 0), nn - 1);
    }
    for (int k = EPG + tid; k < NE; k += 256) { sSrc[k] = k - EPG; sDst[k] = k - EPG; }
    {
        const uint4* gxl = (const uint4*)(xlb + (size_t)g * nn * 256);
        const uint4* gxr = (const uint4*)(xrb + (size_t)g * nn * 256);
        for (int k = tid; k < nn * 32; k += 256) {
            int node = k >> 5, c8 = k & 31;
            *(uint4*)(sXL + node * XLS + c8 * 8) = gxl[k];
            *(uint4*)(sXR + k * 8) = gxr[k];
        }
    }
    if (tid < 32) sCnt[tid] = 0;
    __syncthreads();

    // Phase 0b: histogram -> parallel exclusive scan -> scatter
    for (int k = tid; k < NE; k += 256) atomicAdd(&sCnt[sDst[k]], 1);
    __syncthreads();
    if (tid < 32) {
        int acc = 0, last = 0;
        #pragma unroll
        for (int j = 0; j < 32; ++j) {
            int c = sCnt[j];
            if (j < tid) acc += c;
            if (j == 31) last = c;
        }
        sOff[tid] = acc;
        if (tid == 31) sOff[32] = acc + last;
        sCnt[tid] = 0;                        // same wave, lockstep: reads above done
    }
    __syncthreads();
    for (int k = tid; k < NE; k += 256) {
        int d = sDst[k];
        int p = atomicAdd(&sCnt[d], 1);
        sList[sOff[d] + p] = k;
    }

    // ei echo (independent of phases)
    for (int k = tid; k < NE; k += 256) {
        int s, d; size_t eg;
        if (k < EPG) { s = g * nn + sSrc[k]; d = g * nn + sDst[k]; eg = (size_t)g * EPG + k; }
        else { int node = g * nn + (k - EPG); s = d = node; eg = (size_t)E0 + (size_t)g * nn + (k - EPG); }
        dei[eg] = (float)s;
        dei[(size_t)ET + eg] = (float)d;
    }
    __syncthreads();

    // Phase 1: wave-per-edge scores
    const float4 attv = *(const float4*)(att + lane * 4);
    const int h4 = lane >> 4;
    for (int i = wv; i < NE; i += 4) {
        int srcl = sSrc[i], dstl = sDst[i];
        bf16x4 a = *(const bf16x4*)(sXL + srcl * XLS + lane * 4);
        bf16x4 b = *(const bf16x4*)(sXR + dstl * 256 + lane * 4);
        float p = 0.f;
        {
            float v0 = (float)a[0] + (float)b[0]; v0 = v0 > 0.f ? v0 : 0.2f * v0; p += v0 * attv.x;
            float v1 = (float)a[1] + (float)b[1]; v1 = v1 > 0.f ? v1 : 0.2f * v1; p += v1 * attv.y;
            float v2 = (float)a[2] + (float)b[2]; v2 = v2 > 0.f ? v2 : 0.2f * v2; p += v2 * attv.z;
            float v3 = (float)a[3] + (float)b[3]; v3 = v3 > 0.f ? v3 : 0.2f * v3; p += v3 * attv.w;
        }
        p += __shfl_xor(p, 1); p += __shfl_xor(p, 2);
        p += __shfl_xor(p, 4); p += __shfl_xor(p, 8);
        if ((lane & 15) == 0)
            sExp[i * 4 + h4] = __expf(fminf(fmaxf(p, -60.f), 60.f));
    }
    __syncthreads();

    // Phase 2: 8-lane group per dst node; lane owns 32 channels
    const int grp  = wv * 8 + (lane >> 3);    // dst node 0..31
    const int s8   = lane & 7;
    const int chb  = s8 * 32;
    const int head = s8 >> 1;
    bf* hrow = hbuf + ((size_t)g * 32 + grp) * 256 + chb;

    if (grp < nn) {
        const int beg = sOff[grp], end = sOff[grp + 1];
        float den = 0.f;
        f32x4 acc[8];
        #pragma unroll
        for (int k2 = 0; k2 < 8; ++k2) acc[k2] = 0.f;

        for (int q = beg; q < end; ++q) {
            int e = sList[q];
            float ev = sExp[e * 4 + head];
            den += ev;
            const __bf16* xp = sXL + sSrc[e] * XLS + chb;
            #pragma unroll
            for (int k2 = 0; k2 < 4; ++k2) {
                bf16x8 xa = *(const bf16x8*)(xp + k2 * 8);
                #pragma unroll
                for (int j = 0; j < 4; ++j)
                    acc[k2 * 2][j]     += ev * (float)xa[j];
                #pragma unroll
                for (int j = 0; j < 4; ++j)
                    acc[k2 * 2 + 1][j] += ev * (float)xa[4 + j];
            }
        }
        const float rden = 1.f / fmaxf(den, 1e-30f);

        // alpha echo: lanes s8 in {0,2,4,6} cover heads 0..3; 16B coalesced/edge
        if (!(s8 & 1)) {
            for (int q = beg; q < end; ++q) {
                int e = sList[q];
                float al = fminf(fmaxf(sExp[e * 4 + head] * rden, 0.f), 1.f);
                size_t eg = (e < EPG) ? ((size_t)g * EPG + e)
                                      : ((size_t)E0 + (size_t)g * nn + (e - EPG));
                dalpha[eg * 4 + head] = al;
            }
        }

        #pragma unroll
        for (int k2 = 0; k2 < 8; ++k2) {
            float4 gbv = *(const float4*)(gbias + chb + k2 * 4);
            bf16x4 o;
            o[0] = (__bf16)clamp256(fmaxf(acc[k2][0] * rden + gbv.x, 0.f));
            o[1] = (__bf16)clamp256(fmaxf(acc[k2][1] * rden + gbv.y, 0.f));
            o[2] = (__bf16)clamp256(fmaxf(acc[k2][2] * rden + gbv.z, 0.f));
            o[3] = (__bf16)clamp256(fmaxf(acc[k2][3] * rden + gbv.w, 0.f));
            *(bf16x4*)(hrow + k2 * 4) = o;
        }
    } else {
        bf16x4 z; z[0] = (__bf16)0.f; z[1] = (__bf16)0.f; z[2] = (__bf16)0.f; z[3] = (__bf16)0.f;
        #pragma unroll
        for (int k2 = 0; k2 < 8; ++k2)
            *(bf16x4*)(hrow + k2 * 4) = z;
    }
}

// ---- fused weight prep ----
struct CvtSegs { const float* in[7]; bf* out[7]; int n[7]; };
__global__ void prep_cvt(CvtSegs s, int total)
{
    int idx = blockIdx.x * 256 + threadIdx.x;
    if (idx >= total) return;
    #pragma unroll
    for (int i = 0; i < 7; ++i) {
        if (idx < s.n[i]) { s.out[i][idx] = __float2bfloat16(s.in[i][idx]); return; }
        idx -= s.n[i];
    }
}
struct TapSegs { const float* w[3]; bf* o[3]; int cc[3]; };
__global__ void prep_taps3(TapSegs s, int total)
{
    int idx = blockIdx.x * 256 + threadIdx.x;
    if (idx >= total) return;
    #pragma unroll
    for (int i = 0; i < 3; ++i) {
        if (idx < s.cc[i]) {
            #pragma unroll
            for (int k = 0; k < 3; ++k)
                s.o[i][(size_t)k * s.cc[i] + idx] = __float2bfloat16(s.w[i][(size_t)idx * 3 + k]);
            return;
        }
        idx -= s.cc[i];
    }
}

// fc1_w f32 [F1][ci*nn+l] -> bf16 W1t [F1][l*HC+ci], l padded to 32
__global__ void prep_fc1(const float* __restrict__ w, bf* __restrict__ o, int F1, int nn, int HC)
{
    int idx = blockIdx.x * 256 + threadIdx.x;
    int kw = 32 * HC;
    if (idx >= F1 * kw) return;
    int co = idx / kw, r = idx % kw, l = r / HC, ci = r % HC;
    float hv = 0.f;
    if (l < nn) hv = w[(size_t)co * (HC * nn) + ci * nn + l];
    o[idx] = __float2bfloat16(hv);
}

// fc1 split-K reduce: z1 = bf16(relu(sum_z partials + bias))
__global__ void fc1red(const bf* __restrict__ zp, const float* __restrict__ bias,
                       bf* __restrict__ o, int MN, int N, int S)
{
    int idx = blockIdx.x * 256 + threadIdx.x;
    if (idx >= MN) return;
    float s = 0.f;
    for (int z = 0; z < S; ++z) s += __bfloat162float(zp[(size_t)z * MN + idx]);
    o[idx] = __float2bfloat16(clamp256(fmaxf(s + bias[idx % N], 0.f)));
}

extern "C" void kernel_launch(void* const* d_in, const int* in_sizes, int n_in,
                              void* d_out, int out_size, void* d_ws, size_t ws_size,
                              hipStream_t stream)
{
    (void)n_in; (void)ws_size;
    const float* x   = (const float*)d_in[0];
    const float* Wl  = (const float*)d_in[1];  const float* bl  = (const float*)d_in[2];
    const float* Wr  = (const float*)d_in[3];  const float* br  = (const float*)d_in[4];
    const float* att = (const float*)d_in[5];  const float* gb  = (const float*)d_in[6];
    const float* t0w = (const float*)d_in[7];  const float* t0b = (const float*)d_in[8];
    const float* l0w = (const float*)d_in[9];  const float* l0b = (const float*)d_in[10];
    const float* t1w = (const float*)d_in[11]; const float* t1b = (const float*)d_in[12];
    const float* l1w = (const float*)d_in[13]; const float* l1b = (const float*)d_in[14];
    const float* d1w = (const float*)d_in[15]; const float* d1b = (const float*)d_in[16];
    const float* t2w = (const float*)d_in[17]; const float* t2b = (const float*)d_in[18];
    const float* l2w = (const float*)d_in[19]; const float* l2b = (const float*)d_in[20];
    const float* d2w = (const float*)d_in[21]; const float* d2b = (const float*)d_in[22];
    const float* f1w = (const float*)d_in[23]; const float* f1b = (const float*)d_in[24];
    const float* f2w = (const float*)d_in[25]; const float* f2b = (const float*)d_in[26];
    const float* f3w = (const float*)d_in[27]; const float* f3b = (const float*)d_in[28];
    const int*   ei  = (const int*)d_in[29];

    const int HC   = in_sizes[6];                        // 256
    const int F_IN = in_sizes[1] / (HC > 0 ? HC : 1);    // 64
    const int NN   = in_sizes[0] / (F_IN > 0 ? F_IN : 1);// 30720
    const int E0   = in_sizes[29] / 2;                   // 245760
    const int ET   = E0 + NN;                            // 276480
    int nn = in_sizes[9];  nn = nn < 1 ? 1 : (nn > 32 ? 32 : nn);  // 30
    const int NG   = NN / nn;                            // 1024
    const int EPG  = NG > 0 ? E0 / NG : 0;               // 240
    const int C1   = in_sizes[12];                       // 512
    const int C2   = in_sizes[18];                       // 256
    const int F1   = in_sizes[24];                       // 512
    const int F2   = in_sizes[26];                       // 256
    const int F3   = in_sizes[28];                       // 144
    const int NG2  = (NG + 1) / 2;

    float* dout   = (float*)d_out;
    float* dei    = dout + ((size_t)out_size - 2 * (size_t)ET);
    float* dalpha = dei - (size_t)ET * 4;

    // ---- workspace: [0,4M) xb | [4M,7M) weights | S0 18MB | S1 17MB = 42MB ----
    char* ws = (char*)d_ws;
    const size_t MB = 1ull << 20;
    bf*    xb   = (bf*)(ws);
    bf*    WkA  = (bf*)(ws + 4 * MB);
    bf*    WkB  = WkA + (size_t)3 * HC * HC;
    bf*    WkC  = WkB + (size_t)3 * C1 * HC;
    bf*    Wlb  = WkC + (size_t)3 * C2 * C1;
    bf*    Wrb  = Wlb + (size_t)HC * F_IN;
    bf*    f2wb = Wrb + (size_t)HC * F_IN;
    bf*    f3wb = f2wb + (size_t)F2 * F1;
    bf*    d1wb = f3wb + (size_t)F3 * F2;
    bf*    d2wb = d1wb + (size_t)C1 * HC;
    const size_t S0 = 7 * MB;
    const size_t S1 = 25 * MB;
    bf*    xrb  = (bf*)(ws + S0);            // S0: xrb -> hbuf -> y1c -> fc stage
    bf*    hbuf = (bf*)(ws + S0);
    bf*    y1c  = (bf*)(ws + S0);
    bf*    W1t  = (bf*)(ws + S0);                        // 8.4 MB
    bf*    z1p  = (bf*)(ws + S0 + (size_t)(8.5 * MB));   // 8 MB (8 x 1MB bf16 partials)
    bf*    z1   = (bf*)(ws + S0 + (size_t)(16.5 * MB));  // 1 MB
    bf*    z2   = (bf*)(ws + S0 + (size_t)(17.5 * MB));  // 0.5 MB
    bf*    xlb  = (bf*)(ws + S1);            // S1: xlb -> y0 -> y2 (in place)
    bf*    y0   = (bf*)(ws + S1);
    bf*    y2   = (bf*)(ws + S1);

    // ---- fused weight prep ----
    {
        CvtSegs cs;
        cs.in[0] = x;   cs.out[0] = xb;   cs.n[0] = NN * F_IN;
        cs.in[1] = Wl;  cs.out[1] = Wlb;  cs.n[1] = HC * F_IN;
        cs.in[2] = Wr;  cs.out[2] = Wrb;  cs.n[2] = HC * F_IN;
        cs.in[3] = f2w; cs.out[3] = f2wb; cs.n[3] = F2 * F1;
        cs.in[4] = f3w; cs.out[4] = f3wb; cs.n[4] = F3 * F2;
        cs.in[5] = d1w; cs.out[5] = d1wb; cs.n[5] = C1 * HC;
        cs.in[6] = d2w; cs.out[6] = d2wb; cs.n[6] = C2 * C1;
        int tot = 0; for (int i = 0; i < 7; ++i) tot += cs.n[i];
        prep_cvt<<<(tot + 255) / 256, 256, 0, stream>>>(cs, tot);
        TapSegs ts;
        ts.w[0] = t0w; ts.o[0] = WkA; ts.cc[0] = HC * HC;
        ts.w[1] = t1w; ts.o[1] = WkB; ts.cc[1] = C1 * HC;
        ts.w[2] = t2w; ts.o[2] = WkC; ts.cc[2] = C2 * C1;
        int tt = ts.cc[0] + ts.cc[1] + ts.cc[2];
        prep_taps3<<<(tt + 255) / 256, 256, 0, stream>>>(ts, tt);
    }

    // ---- GAT transforms: single dual-output GEMM (mode 5) ----
    gemm_tf<1, true><<<dim3((HC + 63) / 64, (NN + 63) / 64), 256, 0, stream>>>(
        xb, Wlb, Wrb, bl, br, nullptr, nullptr, (const bf*)xrb, HC,
        xlb, nullptr, HC, NN, HC, F_IN, 1, 5, 0, 0, nn, F_IN);

    // ---- fused GAT edge/softmax/aggregate (latency-flattened v3) ----
    gat_fused3<<<NG, 256, 0, stream>>>(ei, xlb, xrb, att, gb, hbuf, dalpha, dei,
                                       E0, ET, EPG, nn);

    // ---- TCN block 0 ----
    const bool fast0 = ((NG * 32) % 128 == 0) && (HC % 64 == 0) && (HC % 32 == 0);
    if (fast0)
        gemm_tcn<3, false><<<dim3(HC / 64, NG * 32 / 128), 256, 0, stream>>>(
            hbuf, WkA, nullptr, t0b, nullptr, l0w, l0b, hbuf, HC,
            y0, HC, NG * 32, HC, HC, 1, nn);
    else
        gemm_tf<3, false><<<dim3((HC + 63) / 64, NG * 32 / 64), 256, 0, stream>>>(
            hbuf, WkA, nullptr, t0b, nullptr, l0w, l0b, hbuf, HC,
            y0, nullptr, HC, NG * 32, HC, HC, 1, 2, 0, 1, nn, HC);

    // ---- TCN blocks 1 & 2, two graph-chunks ----
    for (int c = 0; c < 2; ++c) {
        int g0 = c * NG2;
        int gc = (c == 0) ? NG2 : (NG - NG2);
        if (gc <= 0) continue;
        const bf* y0c = y0 + (size_t)g0 * 32 * HC;
        bf*       y2c = y0 + (size_t)g0 * 32 * HC;
        const bool fastc = ((gc * 32) % 128 == 0) && (C1 % 64 == 0) && (C2 % 64 == 0)
                           && (HC % 32 == 0) && (C1 % 32 == 0);
        if (fastc) {
            gemm_tcn<3, true><<<dim3(C1 / 64, gc * 32 / 128), 256, 0, stream>>>(
                y0c, WkB, d1wb, t1b, d1b, l1w, l1b, nullptr, 0,
                y1c, C1, gc * 32, C1, HC, 2, nn);
            gemm_tcn<3, true><<<dim3(C2 / 64, gc * 32 / 128), 256, 0, stream>>>(
                y1c, WkC, d2wb, t2b, d2b, l2w, l2b, nullptr, 0,
                y2c, C2, gc * 32, C2, C1, 4, nn);
        } else {
            gemm_tf<3, true><<<dim3((C1 + 63) / 64, gc * 32 / 64), 256, 0, stream>>>(
                y0c, WkB, d1wb, t1b, d1b, l1w, l1b, nullptr, 0,
                y1c, nullptr, C1, gc * 32, C1, HC, 2, 2, 0, 1, nn, HC);
            gemm_tf<3, true><<<dim3((C2 + 63) / 64, gc * 32 / 64), 256, 0, stream>>>(
                y1c, WkC, d2wb, t2b, d2b, l2w, l2b, nullptr, 0,
                y2c, nullptr, C2, gc * 32, C2, C1, 4, 2, 0, 1, nn, C1);
        }
    }

    // ---- FC head ----
    prep_fc1<<<(F1 * 32 * HC + 255) / 256, 256, 0, stream>>>(f1w, W1t, F1, nn, HC);
    gemm_tf<1, false><<<dim3((F1 + 63) / 64, (NG + 63) / 64, 8), 256, 0, stream>>>(
        y2, W1t, nullptr, nullptr, nullptr, nullptr, nullptr, nullptr, 0,
        z1p, nullptr, F1, NG, F1, 32 * HC, 1, 3, 0, 0, nn, 4 * HC);
    fc1red<<<(NG * F1 + 255) / 256, 256, 0, stream>>>(z1p, f1b, z1, NG * F1, F1, 8);

    gemm_tf<1, false><<<dim3((F2 + 63) / 64, (NG + 63) / 64), 256, 0, stream>>>(
        z1, f2wb, nullptr, f2b, nullptr, nullptr, nullptr, nullptr, 0,
        z2, nullptr, F2, NG, F2, F1, 1, 0, 1, 0, nn, F1);
    gemm_tf<1, false><<<dim3((F3 + 63) / 64, (NG + 63) / 64), 256, 0, stream>>>(
        z2, f3wb, nullptr, f3b, nullptr, nullptr, nullptr, nullptr, 0,
        nullptr, dout, F3, NG, F3, F2, 1, 0, 0, 0, nn, F2);
}

// Round 4
// 526.408 us; speedup vs baseline: 1.1324x; 1.1324x over previous
//
#include <hip/hip_runtime.h>
#include <hip/hip_bf16.h>

typedef __bf16  bf16x8 __attribute__((ext_vector_type(8)));
typedef __bf16  bf16x4 __attribute__((ext_vector_type(4)));
typedef float   f32x4  __attribute__((ext_vector_type(4)));
typedef __hip_bfloat16 bf;

__device__ __forceinline__ float clamp256(float v) {
    return fminf(fmaxf(v, -256.f), 256.f);
}
__device__ __forceinline__ float sane(float v) {
    return fminf(fmaxf(v, -1e4f), 1e4f);
}
// 16B-chunk XOR swizzle baked into weight layout: spreads B-tile rows over
// 8 LDS bank-groups (2-way = free) while keeping global_load_lds linear.
__device__ __forceinline__ int swzk(int k, int col) {
    return (k & ~31) | ((((k >> 3) & 3) ^ ((col >> 1) & 3)) << 3) | (k & 7);
}

// ---------------------------------------------------------------------------
// Tap-fused, register-prefetch 64x64 bf16 MFMA GEMM (legacy: GAT + FC head).
// mode 0: store (+bias,relu) -> outb bf16 or outf f32
// mode 2: register-resident LayerNorm(nn)+relu+residual (accR/Wd or res[])
// mode 3: split-K bf16 partials: outb[z*M*ostride + row*ostride + col]
// mode 5: dual output (HASWD): outb=accC+bias, res(cast bf*)=accR+biasd
// NOTE: expects UNSWIZZLED weights (GAT/FC paths).
// ---------------------------------------------------------------------------
template<int TAPS, bool HASWD>
__global__ __launch_bounds__(256) void gemm_tf(
    const bf* __restrict__ A, const bf* __restrict__ Wt, const bf* __restrict__ Wd,
    const float* __restrict__ bias, const float* __restrict__ biasd,
    const float* __restrict__ lnw, const float* __restrict__ lnb,
    const bf* __restrict__ res, int res_stride,
    bf* __restrict__ outb, float* __restrict__ outf, int out_stride,
    int M, int N, int K, int dil, int mode, int relu, int padded, int nn, int kLen)
{
    constexpr int NT = TAPS + (HASWD ? 1 : 0);
    __shared__ __align__(16) unsigned short sA[66 * 40];      // 64 rows + zero row 64
    __shared__ __align__(16) unsigned short sB[NT][64 * 40];
    __shared__ float sS[4][64], sS2[4][64];

    const int tid  = threadIdx.x;
    const int wv   = tid >> 6;
    const int lane = tid & 63;
    const int m0   = blockIdx.y * 64;
    const int n0   = blockIdx.x * 64;
    const int frow = lane & 15;
    const int fq   = lane >> 4;
    const int kOff = blockIdx.z * kLen;
    const int kEnd = (kOff + kLen < K) ? (kOff + kLen) : K;

    if (tid < 40) sA[64 * 40 + tid] = (unsigned short)0;

    int aoff[NT];
    {
        int token = wv * 16 + frow;
        int b = token >> 5, l = token & 31;
        #pragma unroll
        for (int t = 0; t < NT; ++t) {
            int s = (t < TAPS) ? (t - TAPS / 2) * dil : 0;
            int ar;
            if (padded) {
                int ls = l + s;
                ar = ((unsigned)ls < 32u) ? (b * 32 + ls) : 64;
            } else {
                ar = token;
            }
            aoff[t] = ar * 40 + fq * 8;
        }
    }

    const int srow = tid >> 2;
    const int schk = (tid & 3) << 3;
    int raG = m0 + srow;
    if (!padded && raG >= M) raG = -1;
    const int rbG  = n0 + srow;
    const bool bval = rbG < N;
    const bf* Ap = (raG >= 0) ? (A + (size_t)raG * K) : nullptr;
    const bf* Bp[NT];
    #pragma unroll
    for (int t = 0; t < NT; ++t)
        Bp[t] = (HASWD && t == TAPS) ? (Wd + (size_t)rbG * K)
                                     : (Wt + ((size_t)t * N + rbG) * K);

    f32x4 accC[4], accR[4];
    #pragma unroll
    for (int i = 0; i < 4; ++i) { accC[i] = 0.f; accR[i] = 0.f; }

    const uint4 zu = make_uint4(0u, 0u, 0u, 0u);
    uint4 pa, pb[NT];
    pa = Ap ? *(const uint4*)(Ap + kOff + schk) : zu;
    #pragma unroll
    for (int t = 0; t < NT; ++t)
        pb[t] = bval ? *(const uint4*)(Bp[t] + kOff + schk) : zu;

    for (int kb = kOff; kb < kEnd; kb += 32) {
        __syncthreads();
        *(uint4*)(sA + srow * 40 + schk) = pa;
        #pragma unroll
        for (int t = 0; t < NT; ++t)
            *(uint4*)(&sB[t][srow * 40 + schk]) = pb[t];
        __syncthreads();
        int kn = kb + 32;
        if (kn < kEnd) {
            pa = Ap ? *(const uint4*)(Ap + kn + schk) : zu;
            #pragma unroll
            for (int t = 0; t < NT; ++t)
                pb[t] = bval ? *(const uint4*)(Bp[t] + kn + schk) : zu;
        }
        #pragma unroll
        for (int t = 0; t < TAPS; ++t) {
            bf16x8 af = *(const bf16x8*)(sA + aoff[t]);
            #pragma unroll
            for (int nt = 0; nt < 4; ++nt) {
                bf16x8 bg = *(const bf16x8*)(&sB[t][(nt * 16 + frow) * 40 + fq * 8]);
                accC[nt] = __builtin_amdgcn_mfma_f32_16x16x32_bf16(af, bg, accC[nt], 0, 0, 0);
            }
        }
        if constexpr (HASWD) {
            bf16x8 af = *(const bf16x8*)(sA + aoff[TAPS]);
            #pragma unroll
            for (int nt = 0; nt < 4; ++nt) {
                bf16x8 bg = *(const bf16x8*)(&sB[TAPS][(nt * 16 + frow) * 40 + fq * 8]);
                accR[nt] = __builtin_amdgcn_mfma_f32_16x16x32_bf16(af, bg, accR[nt], 0, 0, 0);
            }
        }
    }

    if (mode == 0) {
        #pragma unroll
        for (int nt = 0; nt < 4; ++nt) {
            int col = n0 + nt * 16 + frow;
            if (col >= N) continue;
            float bv = bias ? bias[col] : 0.f;
            #pragma unroll
            for (int r = 0; r < 4; ++r) {
                int row = m0 + wv * 16 + fq * 4 + r;
                if (row >= M) continue;
                float v = accC[nt][r] + bv;
                if (relu) v = fmaxf(v, 0.f);
                if (outb) outb[(size_t)row * out_stride + col] = __float2bfloat16(clamp256(v));
                else      outf[(size_t)row * out_stride + col] = sane(v);
            }
        }
    } else if (mode == 3) {
        bf* po = outb + (size_t)blockIdx.z * M * out_stride;
        #pragma unroll
        for (int nt = 0; nt < 4; ++nt) {
            int col = n0 + nt * 16 + frow;
            if (col >= N) continue;
            #pragma unroll
            for (int r = 0; r < 4; ++r) {
                int row = m0 + wv * 16 + fq * 4 + r;
                if (row >= M) continue;
                po[(size_t)row * out_stride + col] = __float2bfloat16(accC[nt][r]);
            }
        }
    } else if (mode == 5) {
        if constexpr (HASWD) {
            bf* out2 = (bf*)res;
            #pragma unroll
            for (int nt = 0; nt < 4; ++nt) {
                int col = n0 + nt * 16 + frow;
                if (col >= N) continue;
                float bv = bias[col], bd = biasd[col];
                #pragma unroll
                for (int r = 0; r < 4; ++r) {
                    int row = m0 + wv * 16 + fq * 4 + r;
                    if (row >= M) continue;
                    outb[(size_t)row * out_stride + col] = __float2bfloat16(clamp256(accC[nt][r] + bv));
                    out2[(size_t)row * res_stride + col] = __float2bfloat16(clamp256(accR[nt][r] + bd));
                }
            }
        }
    } else {  // mode 2
        float bvc[4], bdc[4];
        #pragma unroll
        for (int nt = 0; nt < 4; ++nt) {
            int col = n0 + nt * 16 + frow;
            bvc[nt] = bias[col];
            bdc[nt] = (HASWD && biasd) ? biasd[col] : 0.f;
        }
        float s[4], s2[4];
        #pragma unroll
        for (int nt = 0; nt < 4; ++nt) { s[nt] = 0.f; s2[nt] = 0.f; }
        #pragma unroll
        for (int nt = 0; nt < 4; ++nt)
            #pragma unroll
            for (int r = 0; r < 4; ++r) {
                int row = wv * 16 + fq * 4 + r;
                int l = row & 31;
                float v = sane(accC[nt][r] + bvc[nt]);
                if (l < nn) { s[nt] += v; s2[nt] += v * v; }
            }
        #pragma unroll
        for (int nt = 0; nt < 4; ++nt) {
            s[nt]  += __shfl_xor(s[nt], 16);  s[nt]  += __shfl_xor(s[nt], 32);
            s2[nt] += __shfl_xor(s2[nt], 16); s2[nt] += __shfl_xor(s2[nt], 32);
        }
        if (fq == 0) {
            #pragma unroll
            for (int nt = 0; nt < 4; ++nt) {
                sS[wv][nt * 16 + frow]  = s[nt];
                sS2[wv][nt * 16 + frow] = s2[nt];
            }
        }
        __syncthreads();
        const int gi = wv >> 1;
        const float inv = 1.f / (float)nn;
        #pragma unroll
        for (int nt = 0; nt < 4; ++nt) {
            int c = nt * 16 + frow;
            int colg = n0 + c;
            float S  = sS[2 * gi][c]  + sS[2 * gi + 1][c];
            float S2 = sS2[2 * gi][c] + sS2[2 * gi + 1][c];
            float mu = S * inv;
            float var = S2 * inv - mu * mu;
            float rs = rsqrtf(fmaxf(var, 0.f) + 1e-5f);
            #pragma unroll
            for (int r = 0; r < 4; ++r) {
                int row = wv * 16 + fq * 4 + r;
                int l = row & 31;
                int grow = m0 + row;
                float outv = 0.f;
                if (l < nn) {
                    float v = (sane(accC[nt][r] + bvc[nt]) - mu) * rs * lnw[l] + lnb[l];
                    v = fmaxf(v, 0.f);
                    float rr;
                    if constexpr (HASWD) rr = sane(accR[nt][r] + bdc[nt]);
                    else rr = __bfloat162float(res[(size_t)grow * res_stride + colg]);
                    outv = clamp256(v + rr);
                }
                outb[(size_t)grow * out_stride + colg] = __float2bfloat16(outv);
            }
        }
    }
}

// ---------------------------------------------------------------------------
// TCN tap-fused GEMM v3: 256x64 macro-tile, 64x64 per wave (MR=4).
// B panels (taps + optional Wd) staged via global_load_lds DMA into a
// DOUBLE-BUFFERED unpadded LDS region; weights are PRE-SWIZZLED at prep
// (chunk ^= (col>>1)&3) so reads are 2-way bank-conflict-free.
// A register-staged into padded sA. acc in AGPRs; ~70 arch VGPR ->
// __launch_bounds__(256,2) = 2 blocks/CU.
// Per wave per K-step: 28 ds_read + 4 ds_write for 64 MFMA (vs 28/22+6 for
// 32 MFMA before) -> ~2.4x less LDS-pipe pressure per FLOP.
// Requires: M % 256 == 0, N % 64 == 0, K % 32 == 0, swizzled weights.
// ---------------------------------------------------------------------------
template<int TAPS, bool HASWD>
__global__ __launch_bounds__(256, 2) void gemm_tcn(
    const bf* __restrict__ A, const bf* __restrict__ Wt, const bf* __restrict__ Wd,
    const float* __restrict__ bias, const float* __restrict__ biasd,
    const float* __restrict__ lnw, const float* __restrict__ lnb,
    const bf* __restrict__ res, int res_stride,
    bf* __restrict__ outb, int out_stride,
    int M, int N, int K, int dil, int nn)
{
    constexpr int NT = TAPS + (HASWD ? 1 : 0);
    __shared__ __align__(16) unsigned short sA[257 * 40];          // 256 rows + zero row
    __shared__ __align__(16) unsigned short sBall[2 * NT * 64 * 32]; // dbuf B, linear

    const int tid  = threadIdx.x;
    const int wv   = tid >> 6;
    const int lane = tid & 63;
    const int frow = lane & 15;
    const int fq   = lane >> 4;

    // XCD-contiguous swizzle (bijective when nwg % 8 == 0)
    const int gx  = gridDim.x;
    const int nwg = gx * gridDim.y;
    int wg = blockIdx.y * gx + blockIdx.x;
    if ((nwg & 7) == 0) wg = (wg & 7) * (nwg >> 3) + (wg >> 3);
    const int n0 = (wg % gx) * 64;
    const int m0 = (wg / gx) * 256;

    if (tid < 40) sA[256 * 40 + tid] = (unsigned short)0;

    // A fragment offsets per (tap, m-rep); zero row = 256
    int aoff[TAPS][4];
    #pragma unroll
    for (int mr = 0; mr < 4; ++mr) {
        int token = wv * 64 + mr * 16 + frow;
        int b5 = token >> 5, l = token & 31;
        #pragma unroll
        for (int t = 0; t < TAPS; ++t) {
            int ls = l + (t - TAPS / 2) * dil;
            int ar = ((unsigned)ls < 32u) ? (b5 * 32 + ls) : 256;
            aoff[t][mr] = ar * 40 + fq * 8;
        }
    }
    // loop-invariant swizzled B chunk offset (shorts)
    const int bco = (fq ^ ((frow >> 1) & 3)) << 3;

    // A staging: thread covers rows {tid>>2 + i*64}, chunk tid&3
    const int srow = tid >> 2;
    const int chS  = (tid & 3) << 3;
    const bf* Ap = A + (size_t)(m0 + srow) * K + chS;

    // B DMA sources: wave wv handles tap wv (one tap per wave), 4 row-groups
    const bf* bsrc[4];
    {
        int lr = lane >> 2, lc = lane & 3;
        #pragma unroll
        for (int i = 0; i < 4; ++i) {
            int colb = n0 + i * 16 + lr;
            const bf* Wb;
            if (HASWD && wv == TAPS) Wb = Wd + (size_t)colb * K;
            else if (wv < TAPS)      Wb = Wt + ((size_t)wv * N + colb) * K;
            else                     Wb = Wt + (size_t)colb * K;   // unused (wv>=NT)
            bsrc[i] = Wb + lc * 8;
        }
    }

    f32x4 accC[4][4], accR[4][4];
    #pragma unroll
    for (int i = 0; i < 4; ++i)
        #pragma unroll
        for (int j = 0; j < 4; ++j) { accC[i][j] = 0.f; if (HASWD) accR[i][j] = 0.f; }

    #define ISSUE_B(BUFB, KBS)                                                      \
        if (wv < NT) {                                                              \
            unsigned short* bas = sBall + ((size_t)((BUFB) * NT + wv) * 64) * 32;   \
            _Pragma("unroll")                                                       \
            for (int i = 0; i < 4; ++i) {                                           \
                __builtin_amdgcn_global_load_lds(                                   \
                    (const __attribute__((address_space(1))) void*)(bsrc[i] + (KBS)), \
                    (__attribute__((address_space(3))) void*)(bas + i * 512),       \
                    16, 0, 0);                                                      \
            }                                                                       \
        }

    uint4 pa[4];
    #pragma unroll
    for (int i = 0; i < 4; ++i) pa[i] = *(const uint4*)(Ap + (size_t)i * 64 * K);
    ISSUE_B(0, 0);

    int buf = 0;
    for (int kb = 0; kb < K; kb += 32) {
        __syncthreads();                       // drains pa loads + B DMA (cur buf)
        #pragma unroll
        for (int i = 0; i < 4; ++i)
            *(uint4*)(sA + (srow + i * 64) * 40 + chS) = pa[i];
        __syncthreads();
        int kn = kb + 32;
        if (kn < K) {
            ISSUE_B(buf ^ 1, kn);              // flies under compute; drained next barrier
            #pragma unroll
            for (int i = 0; i < 4; ++i)
                pa[i] = *(const uint4*)(Ap + (size_t)i * 64 * K + kn);
        }
        const unsigned short* sBb = sBall + (size_t)buf * NT * 2048;
        bf16x8 aMid[4];
        #pragma unroll
        for (int mr = 0; mr < 4; ++mr)
            aMid[mr] = *(const bf16x8*)(sA + aoff[TAPS / 2][mr]);
        #pragma unroll
        for (int t = 0; t < TAPS; ++t) {
            bf16x8 af[4];
            #pragma unroll
            for (int mr = 0; mr < 4; ++mr)
                af[mr] = (t == TAPS / 2) ? aMid[mr]
                                         : *(const bf16x8*)(sA + aoff[t][mr]);
            #pragma unroll
            for (int nt = 0; nt < 4; ++nt) {
                bf16x8 bg = *(const bf16x8*)(sBb + (size_t)t * 2048 + (nt * 16 + frow) * 32 + bco);
                #pragma unroll
                for (int mr = 0; mr < 4; ++mr)
                    accC[mr][nt] = __builtin_amdgcn_mfma_f32_16x16x32_bf16(af[mr], bg, accC[mr][nt], 0, 0, 0);
            }
        }
        if constexpr (HASWD) {
            #pragma unroll
            for (int nt = 0; nt < 4; ++nt) {
                bf16x8 bg = *(const bf16x8*)(sBb + (size_t)TAPS * 2048 + (nt * 16 + frow) * 32 + bco);
                #pragma unroll
                for (int mr = 0; mr < 4; ++mr)
                    accR[mr][nt] = __builtin_amdgcn_mfma_f32_16x16x32_bf16(aMid[mr], bg, accR[mr][nt], 0, 0, 0);
            }
        }
        buf ^= 1;
    }
    #undef ISSUE_B

    // ---- epilogue: in-register LayerNorm(nn) + relu + residual ----
    float bvc[4], bdc[4];
    #pragma unroll
    for (int nt = 0; nt < 4; ++nt) {
        int col = n0 + nt * 16 + frow;
        bvc[nt] = bias[col];
        bdc[nt] = HASWD ? biasd[col] : 0.f;
    }
    float S[2][4], Q[2][4];
    #pragma unroll
    for (int h = 0; h < 2; ++h)
        #pragma unroll
        for (int nt = 0; nt < 4; ++nt) { S[h][nt] = 0.f; Q[h][nt] = 0.f; }
    #pragma unroll
    for (int mr = 0; mr < 4; ++mr) {
        const int h = mr >> 1;
        #pragma unroll
        for (int nt = 0; nt < 4; ++nt)
            #pragma unroll
            for (int r = 0; r < 4; ++r) {
                int l = (mr & 1) * 16 + fq * 4 + r;
                if (l < nn) {
                    float v = sane(accC[mr][nt][r] + bvc[nt]);
                    S[h][nt] += v; Q[h][nt] += v * v;
                }
            }
    }
    const float inv = 1.f / (float)nn;
    float mu[2][4], rsg[2][4];
    #pragma unroll
    for (int h = 0; h < 2; ++h)
        #pragma unroll
        for (int nt = 0; nt < 4; ++nt) {
            float s = S[h][nt], q = Q[h][nt];
            s += __shfl_xor(s, 16); s += __shfl_xor(s, 32);
            q += __shfl_xor(q, 16); q += __shfl_xor(q, 32);
            float m = s * inv;
            float var = q * inv - m * m;
            mu[h][nt]  = m;
            rsg[h][nt] = rsqrtf(fmaxf(var, 0.f) + 1e-5f);
        }
    float lw[2][4], lb2[2][4];
    #pragma unroll
    for (int p = 0; p < 2; ++p)
        #pragma unroll
        for (int r = 0; r < 4; ++r) {
            int l = p * 16 + fq * 4 + r;
            bool ok = l < nn;
            lw[p][r]  = ok ? lnw[l] : 0.f;
            lb2[p][r] = ok ? lnb[l] : 0.f;
        }
    #pragma unroll
    for (int nt = 0; nt < 4; ++nt) {
        const int colg = n0 + nt * 16 + frow;
        #pragma unroll
        for (int mr = 0; mr < 4; ++mr) {
            const int h = mr >> 1, p = mr & 1;
            #pragma unroll
            for (int r = 0; r < 4; ++r) {
                int l = p * 16 + fq * 4 + r;
                int grow = m0 + wv * 64 + mr * 16 + fq * 4 + r;
                float outv = 0.f;
                if (l < nn) {
                    float v = (sane(accC[mr][nt][r] + bvc[nt]) - mu[h][nt]) * rsg[h][nt] * lw[p][r] + lb2[p][r];
                    v = fmaxf(v, 0.f);
                    float rr;
                    if constexpr (HASWD) rr = sane(accR[mr][nt][r] + bdc[nt]);
                    else rr = __bfloat162float(res[(size_t)grow * res_stride + colg]);
                    outv = clamp256(v + rr);
                }
                outb[(size_t)grow * out_stride + colg] = __float2bfloat16(outv);
            }
        }
    }
}

// ---------------------------------------------------------------------------
// Fused per-graph GAT v3: latency-flattened.
// ---------------------------------------------------------------------------
#define MAXNE 270
#define XLS   260   // padded XL row stride (channels)
__global__ __launch_bounds__(256, 4) void gat_fused3(
    const int* __restrict__ ei, const bf* __restrict__ xlb, const bf* __restrict__ xrb,
    const float* __restrict__ att, const float* __restrict__ gbias,
    bf* __restrict__ hbuf, float* __restrict__ dalpha, float* __restrict__ dei,
    int E0, int ET, int EPG, int nn)
{
    __shared__ __align__(16) __bf16 sXL[32 * XLS];   // 16.25 KB (padded rows)
    __shared__ __align__(16) __bf16 sXR[32 * 256];   // 16 KB
    __shared__ float sExp[MAXNE * 4];                // 4.2 KB
    __shared__ int   sSrc[MAXNE], sDst[MAXNE];
    __shared__ int   sList[MAXNE];
    __shared__ int   sCnt[32];
    __shared__ int   sOff[33];

    const int g = blockIdx.x, tid = threadIdx.x, wv = tid >> 6, lane = tid & 63;
    if (EPG + nn > MAXNE) return;
    const int NE = EPG + nn;

    for (int k = tid; k < EPG; k += 256) {
        int s = ei[(size_t)g * EPG + k] - g * nn;
        int d = ei[(size_t)E0 + (size_t)g * EPG + k] - g * nn;
        sSrc[k] = min(max(s, 0), nn - 1);
        sDst[k] = min(max(d, 0), nn - 1);
    }
    for (int k = EPG + tid; k < NE; k += 256) { sSrc[k] = k - EPG; sDst[k] = k - EPG; }
    {
        const uint4* gxl = (const uint4*)(xlb + (size_t)g * nn * 256);
        const uint4* gxr = (const uint4*)(xrb + (size_t)g * nn * 256);
        for (int k = tid; k < nn * 32; k += 256) {
            int node = k >> 5, c8 = k & 31;
            *(uint4*)(sXL + node * XLS + c8 * 8) = gxl[k];
            *(uint4*)(sXR + k * 8) = gxr[k];
        }
    }
    if (tid < 32) sCnt[tid] = 0;
    __syncthreads();

    for (int k = tid; k < NE; k += 256) atomicAdd(&sCnt[sDst[k]], 1);
    __syncthreads();
    if (tid < 32) {
        int acc = 0, last = 0;
        #pragma unroll
        for (int j = 0; j < 32; ++j) {
            int c = sCnt[j];
            if (j < tid) acc += c;
            if (j == 31) last = c;
        }
        sOff[tid] = acc;
        if (tid == 31) sOff[32] = acc + last;
        sCnt[tid] = 0;
    }
    __syncthreads();
    for (int k = tid; k < NE; k += 256) {
        int d = sDst[k];
        int p = atomicAdd(&sCnt[d], 1);
        sList[sOff[d] + p] = k;
    }

    for (int k = tid; k < NE; k += 256) {
        int s, d; size_t eg;
        if (k < EPG) { s = g * nn + sSrc[k]; d = g * nn + sDst[k]; eg = (size_t)g * EPG + k; }
        else { int node = g * nn + (k - EPG); s = d = node; eg = (size_t)E0 + (size_t)g * nn + (k - EPG); }
        dei[eg] = (float)s;
        dei[(size_t)ET + eg] = (float)d;
    }
    __syncthreads();

    const float4 attv = *(const float4*)(att + lane * 4);
    const int h4 = lane >> 4;
    for (int i = wv; i < NE; i += 4) {
        int srcl = sSrc[i], dstl = sDst[i];
        bf16x4 a = *(const bf16x4*)(sXL + srcl * XLS + lane * 4);
        bf16x4 b = *(const bf16x4*)(sXR + dstl * 256 + lane * 4);
        float p = 0.f;
        {
            float v0 = (float)a[0] + (float)b[0]; v0 = v0 > 0.f ? v0 : 0.2f * v0; p += v0 * attv.x;
            float v1 = (float)a[1] + (float)b[1]; v1 = v1 > 0.f ? v1 : 0.2f * v1; p += v1 * attv.y;
            float v2 = (float)a[2] + (float)b[2]; v2 = v2 > 0.f ? v2 : 0.2f * v2; p += v2 * attv.z;
            float v3 = (float)a[3] + (float)b[3]; v3 = v3 > 0.f ? v3 : 0.2f * v3; p += v3 * attv.w;
        }
        p += __shfl_xor(p, 1); p += __shfl_xor(p, 2);
        p += __shfl_xor(p, 4); p += __shfl_xor(p, 8);
        if ((lane & 15) == 0)
            sExp[i * 4 + h4] = __expf(fminf(fmaxf(p, -60.f), 60.f));
    }
    __syncthreads();

    const int grp  = wv * 8 + (lane >> 3);
    const int s8   = lane & 7;
    const int chb  = s8 * 32;
    const int head = s8 >> 1;
    bf* hrow = hbuf + ((size_t)g * 32 + grp) * 256 + chb;

    if (grp < nn) {
        const int beg = sOff[grp], end = sOff[grp + 1];
        float den = 0.f;
        f32x4 acc[8];
        #pragma unroll
        for (int k2 = 0; k2 < 8; ++k2) acc[k2] = 0.f;

        for (int q = beg; q < end; ++q) {
            int e = sList[q];
            float ev = sExp[e * 4 + head];
            den += ev;
            const __bf16* xp = sXL + sSrc[e] * XLS + chb;
            #pragma unroll
            for (int k2 = 0; k2 < 4; ++k2) {
                bf16x8 xa = *(const bf16x8*)(xp + k2 * 8);
                #pragma unroll
                for (int j = 0; j < 4; ++j)
                    acc[k2 * 2][j]     += ev * (float)xa[j];
                #pragma unroll
                for (int j = 0; j < 4; ++j)
                    acc[k2 * 2 + 1][j] += ev * (float)xa[4 + j];
            }
        }
        const float rden = 1.f / fmaxf(den, 1e-30f);

        if (!(s8 & 1)) {
            for (int q = beg; q < end; ++q) {
                int e = sList[q];
                float al = fminf(fmaxf(sExp[e * 4 + head] * rden, 0.f), 1.f);
                size_t eg = (e < EPG) ? ((size_t)g * EPG + e)
                                      : ((size_t)E0 + (size_t)g * nn + (e - EPG));
                dalpha[eg * 4 + head] = al;
            }
        }

        #pragma unroll
        for (int k2 = 0; k2 < 8; ++k2) {
            float4 gbv = *(const float4*)(gbias + chb + k2 * 4);
            bf16x4 o;
            o[0] = (__bf16)clamp256(fmaxf(acc[k2][0] * rden + gbv.x, 0.f));
            o[1] = (__bf16)clamp256(fmaxf(acc[k2][1] * rden + gbv.y, 0.f));
            o[2] = (__bf16)clamp256(fmaxf(acc[k2][2] * rden + gbv.z, 0.f));
            o[3] = (__bf16)clamp256(fmaxf(acc[k2][3] * rden + gbv.w, 0.f));
            *(bf16x4*)(hrow + k2 * 4) = o;
        }
    } else {
        bf16x4 z; z[0] = (__bf16)0.f; z[1] = (__bf16)0.f; z[2] = (__bf16)0.f; z[3] = (__bf16)0.f;
        #pragma unroll
        for (int k2 = 0; k2 < 8; ++k2)
            *(bf16x4*)(hrow + k2 * 4) = z;
    }
}

// ---- fused weight prep ----
struct CvtSegs { const float* in[7]; bf* out[7]; int n[7]; };
__global__ void prep_cvt(CvtSegs s, int total)
{
    int idx = blockIdx.x * 256 + threadIdx.x;
    if (idx >= total) return;
    #pragma unroll
    for (int i = 0; i < 7; ++i) {
        if (idx < s.n[i]) { s.out[i][idx] = __float2bfloat16(s.in[i][idx]); return; }
        idx -= s.n[i];
    }
}
// taps, optionally swizzled for gemm_tcn's global_load_lds path
struct TapSegs { const float* w[3]; bf* o[3]; int cc[3]; int kk[3]; int swz[3]; };
__global__ void prep_taps3(TapSegs s, int total)
{
    int idx = blockIdx.x * 256 + threadIdx.x;
    if (idx >= total) return;
    #pragma unroll
    for (int i = 0; i < 3; ++i) {
        if (idx < s.cc[i]) {
            int K = s.kk[i];
            int co = idx / K, ci = idx % K;
            int dst = co * K + (s.swz[i] ? swzk(ci, co) : ci);
            #pragma unroll
            for (int k = 0; k < 3; ++k)
                s.o[i][(size_t)k * s.cc[i] + dst] = __float2bfloat16(s.w[i][(size_t)idx * 3 + k]);
            return;
        }
        idx -= s.cc[i];
    }
}
// downsample weights, optionally swizzled
__global__ void prep_wswz(const float* __restrict__ w, bf* __restrict__ o,
                          int total, int K, int swz)
{
    int idx = blockIdx.x * 256 + threadIdx.x;
    if (idx >= total) return;
    int co = idx / K, ci = idx % K;
    o[(size_t)co * K + (swz ? swzk(ci, co) : ci)] = __float2bfloat16(w[idx]);
}

// fc1_w f32 [F1][ci*nn+l] -> bf16 W1t [F1][l*HC+ci], l padded to 32
__global__ void prep_fc1(const float* __restrict__ w, bf* __restrict__ o, int F1, int nn, int HC)
{
    int idx = blockIdx.x * 256 + threadIdx.x;
    int kw = 32 * HC;
    if (idx >= F1 * kw) return;
    int co = idx / kw, r = idx % kw, l = r / HC, ci = r % HC;
    float hv = 0.f;
    if (l < nn) hv = w[(size_t)co * (HC * nn) + ci * nn + l];
    o[idx] = __float2bfloat16(hv);
}

// fc1 split-K reduce: z1 = bf16(relu(sum_z partials + bias))
__global__ void fc1red(const bf* __restrict__ zp, const float* __restrict__ bias,
                       bf* __restrict__ o, int MN, int N, int S)
{
    int idx = blockIdx.x * 256 + threadIdx.x;
    if (idx >= MN) return;
    float s = 0.f;
    for (int z = 0; z < S; ++z) s += __bfloat162float(zp[(size_t)z * MN + idx]);
    o[idx] = __float2bfloat16(clamp256(fmaxf(s + bias[idx % N], 0.f)));
}

extern "C" void kernel_launch(void* const* d_in, const int* in_sizes, int n_in,
                              void* d_out, int out_size, void* d_ws, size_t ws_size,
                              hipStream_t stream)
{
    (void)n_in; (void)ws_size;
    const float* x   = (const float*)d_in[0];
    const float* Wl  = (const float*)d_in[1];  const float* bl  = (const float*)d_in[2];
    const float* Wr  = (const float*)d_in[3];  const float* br  = (const float*)d_in[4];
    const float* att = (const float*)d_in[5];  const float* gb  = (const float*)d_in[6];
    const float* t0w = (const float*)d_in[7];  const float* t0b = (const float*)d_in[8];
    const float* l0w = (const float*)d_in[9];  const float* l0b = (const float*)d_in[10];
    const float* t1w = (const float*)d_in[11]; const float* t1b = (const float*)d_in[12];
    const float* l1w = (const float*)d_in[13]; const float* l1b = (const float*)d_in[14];
    const float* d1w = (const float*)d_in[15]; const float* d1b = (const float*)d_in[16];
    const float* t2w = (const float*)d_in[17]; const float* t2b = (const float*)d_in[18];
    const float* l2w = (const float*)d_in[19]; const float* l2b = (const float*)d_in[20];
    const float* d2w = (const float*)d_in[21]; const float* d2b = (const float*)d_in[22];
    const float* f1w = (const float*)d_in[23]; const float* f1b = (const float*)d_in[24];
    const float* f2w = (const float*)d_in[25]; const float* f2b = (const float*)d_in[26];
    const float* f3w = (const float*)d_in[27]; const float* f3b = (const float*)d_in[28];
    const int*   ei  = (const int*)d_in[29];

    const int HC   = in_sizes[6];                        // 256
    const int F_IN = in_sizes[1] / (HC > 0 ? HC : 1);    // 64
    const int NN   = in_sizes[0] / (F_IN > 0 ? F_IN : 1);// 30720
    const int E0   = in_sizes[29] / 2;                   // 245760
    const int ET   = E0 + NN;                            // 276480
    int nn = in_sizes[9];  nn = nn < 1 ? 1 : (nn > 32 ? 32 : nn);  // 30
    const int NG   = NN / nn;                            // 1024
    const int EPG  = NG > 0 ? E0 / NG : 0;               // 240
    const int C1   = in_sizes[12];                       // 512
    const int C2   = in_sizes[18];                       // 256
    const int F1   = in_sizes[24];                       // 512
    const int F2   = in_sizes[26];                       // 256
    const int F3   = in_sizes[28];                       // 144
    const int NG2  = (NG + 1) / 2;

    float* dout   = (float*)d_out;
    float* dei    = dout + ((size_t)out_size - 2 * (size_t)ET);
    float* dalpha = dei - (size_t)ET * 4;

    // ---- fast-path eligibility (must be decided BEFORE weight prep: the
    // gemm_tcn path requires prep-swizzled weights, gemm_tf linear) ----
    const bool fast0 = ((NG * 32) % 256 == 0) && (HC % 64 == 0) && (HC % 32 == 0);
    const int  gcA   = NG2, gcB = NG - NG2;
    const bool fastc = ((gcA * 32) % 256 == 0) && ((gcB * 32) % 256 == 0)
                       && (C1 % 64 == 0) && (C2 % 64 == 0)
                       && (HC % 32 == 0) && (C1 % 32 == 0);

    // ---- workspace: [0,4M) xb | [4M,7M) weights | S0 18MB | S1 17MB = 42MB ----
    char* ws = (char*)d_ws;
    const size_t MB = 1ull << 20;
    bf*    xb   = (bf*)(ws);
    bf*    WkA  = (bf*)(ws + 4 * MB);
    bf*    WkB  = WkA + (size_t)3 * HC * HC;
    bf*    WkC  = WkB + (size_t)3 * C1 * HC;
    bf*    Wlb  = WkC + (size_t)3 * C2 * C1;
    bf*    Wrb  = Wlb + (size_t)HC * F_IN;
    bf*    f2wb = Wrb + (size_t)HC * F_IN;
    bf*    f3wb = f2wb + (size_t)F2 * F1;
    bf*    d1wb = f3wb + (size_t)F3 * F2;
    bf*    d2wb = d1wb + (size_t)C1 * HC;
    const size_t S0 = 7 * MB;
    const size_t S1 = 25 * MB;
    bf*    xrb  = (bf*)(ws + S0);            // S0: xrb -> hbuf -> y1c -> fc stage
    bf*    hbuf = (bf*)(ws + S0);
    bf*    y1c  = (bf*)(ws + S0);
    bf*    W1t  = (bf*)(ws + S0);                        // 8.4 MB
    bf*    z1p  = (bf*)(ws + S0 + (size_t)(8.5 * MB));   // 8 MB (8 x 1MB bf16 partials)
    bf*    z1   = (bf*)(ws + S0 + (size_t)(16.5 * MB));  // 1 MB
    bf*    z2   = (bf*)(ws + S0 + (size_t)(17.5 * MB));  // 0.5 MB
    bf*    xlb  = (bf*)(ws + S1);            // S1: xlb -> y0 -> y2 (in place)
    bf*    y0   = (bf*)(ws + S1);
    bf*    y2   = (bf*)(ws + S1);

    // ---- fused weight prep ----
    {
        CvtSegs cs;
        cs.in[0] = x;   cs.out[0] = xb;   cs.n[0] = NN * F_IN;
        cs.in[1] = Wl;  cs.out[1] = Wlb;  cs.n[1] = HC * F_IN;
        cs.in[2] = Wr;  cs.out[2] = Wrb;  cs.n[2] = HC * F_IN;
        cs.in[3] = f2w; cs.out[3] = f2wb; cs.n[3] = F2 * F1;
        cs.in[4] = f3w; cs.out[4] = f3wb; cs.n[4] = F3 * F2;
        cs.in[5] = nullptr; cs.out[5] = nullptr; cs.n[5] = 0;
        cs.in[6] = nullptr; cs.out[6] = nullptr; cs.n[6] = 0;
        int tot = 0; for (int i = 0; i < 5; ++i) tot += cs.n[i];
        prep_cvt<<<(tot + 255) / 256, 256, 0, stream>>>(cs, tot);
        TapSegs ts;
        ts.w[0] = t0w; ts.o[0] = WkA; ts.cc[0] = HC * HC; ts.kk[0] = HC; ts.swz[0] = fast0 ? 1 : 0;
        ts.w[1] = t1w; ts.o[1] = WkB; ts.cc[1] = C1 * HC; ts.kk[1] = HC; ts.swz[1] = fastc ? 1 : 0;
        ts.w[2] = t2w; ts.o[2] = WkC; ts.cc[2] = C2 * C1; ts.kk[2] = C1; ts.swz[2] = fastc ? 1 : 0;
        int tt = ts.cc[0] + ts.cc[1] + ts.cc[2];
        prep_taps3<<<(tt + 255) / 256, 256, 0, stream>>>(ts, tt);
        prep_wswz<<<(C1 * HC + 255) / 256, 256, 0, stream>>>(d1w, d1wb, C1 * HC, HC, fastc ? 1 : 0);
        prep_wswz<<<(C2 * C1 + 255) / 256, 256, 0, stream>>>(d2w, d2wb, C2 * C1, C1, fastc ? 1 : 0);
    }

    // ---- GAT transforms: single dual-output GEMM (mode 5) ----
    gemm_tf<1, true><<<dim3((HC + 63) / 64, (NN + 63) / 64), 256, 0, stream>>>(
        xb, Wlb, Wrb, bl, br, nullptr, nullptr, (const bf*)xrb, HC,
        xlb, nullptr, HC, NN, HC, F_IN, 1, 5, 0, 0, nn, F_IN);

    // ---- fused GAT edge/softmax/aggregate (latency-flattened v3) ----
    gat_fused3<<<NG, 256, 0, stream>>>(ei, xlb, xrb, att, gb, hbuf, dalpha, dei,
                                       E0, ET, EPG, nn);

    // ---- TCN block 0 ----
    if (fast0)
        gemm_tcn<3, false><<<dim3(HC / 64, NG * 32 / 256), 256, 0, stream>>>(
            hbuf, WkA, nullptr, t0b, nullptr, l0w, l0b, hbuf, HC,
            y0, HC, NG * 32, HC, HC, 1, nn);
    else
        gemm_tf<3, false><<<dim3((HC + 63) / 64, NG * 32 / 64), 256, 0, stream>>>(
            hbuf, WkA, nullptr, t0b, nullptr, l0w, l0b, hbuf, HC,
            y0, nullptr, HC, NG * 32, HC, HC, 1, 2, 0, 1, nn, HC);

    // ---- TCN blocks 1 & 2, two graph-chunks ----
    for (int c = 0; c < 2; ++c) {
        int g0 = c * NG2;
        int gc = (c == 0) ? NG2 : (NG - NG2);
        if (gc <= 0) continue;
        const bf* y0c = y0 + (size_t)g0 * 32 * HC;
        bf*       y2c = y0 + (size_t)g0 * 32 * HC;
        if (fastc) {
            gemm_tcn<3, true><<<dim3(C1 / 64, gc * 32 / 256), 256, 0, stream>>>(
                y0c, WkB, d1wb, t1b, d1b, l1w, l1b, nullptr, 0,
                y1c, C1, gc * 32, C1, HC, 2, nn);
            gemm_tcn<3, true><<<dim3(C2 / 64, gc * 32 / 256), 256, 0, stream>>>(
                y1c, WkC, d2wb, t2b, d2b, l2w, l2b, nullptr, 0,
                y2c, C2, gc * 32, C2, C1, 4, nn);
        } else {
            gemm_tf<3, true><<<dim3((C1 + 63) / 64, gc * 32 / 64), 256, 0, stream>>>(
                y0c, WkB, d1wb, t1b, d1b, l1w, l1b, nullptr, 0,
                y1c, nullptr, C1, gc * 32, C1, HC, 2, 2, 0, 1, nn, HC);
            gemm_tf<3, true><<<dim3((C2 + 63) / 64, gc * 32 / 64), 256, 0, stream>>>(
                y1c, WkC, d2wb, t2b, d2b, l2w, l2b, nullptr, 0,
                y2c, nullptr, C2, gc * 32, C2, C1, 4, 2, 0, 1, nn, C1);
        }
    }

    // ---- FC head ----
    prep_fc1<<<(F1 * 32 * HC + 255) / 256, 256, 0, stream>>>(f1w, W1t, F1, nn, HC);
    gemm_tf<1, false><<<dim3((F1 + 63) / 64, (NG + 63) / 64, 8), 256, 0, stream>>>(
        y2, W1t, nullptr, nullptr, nullptr, nullptr, nullptr, nullptr, 0,
        z1p, nullptr, F1, NG, F1, 32 * HC, 1, 3, 0, 0, nn, 4 * HC);
    fc1red<<<(NG * F1 + 255) / 256, 256, 0, stream>>>(z1p, f1b, z1, NG * F1, F1, 8);

    gemm_tf<1, false><<<dim3((F2 + 63) / 64, (NG + 63) / 64), 256, 0, stream>>>(
        z1, f2wb, nullptr, f2b, nullptr, nullptr, nullptr, nullptr, 0,
        z2, nullptr, F2, NG, F2, F1, 1, 0, 1, 0, nn, F1);
    gemm_tf<1, false><<<dim3((F3 + 63) / 64, (NG + 63) / 64), 256, 0, stream>>>(
        z2, f3wb, nullptr, f3b, nullptr, nullptr, nullptr, nullptr, 0,
        nullptr, dout, F3, NG, F3, F2, 1, 0, 0, 0, nn, F2);
}